// Round 8
// baseline (136.676 us; speedup 1.0000x reference)
//
#include <hip/hip_runtime.h>
#include <hip/hip_bf16.h>
#include <math.h>

typedef __bf16 bf16x8 __attribute__((ext_vector_type(8)));
typedef float floatx4 __attribute__((ext_vector_type(4)));

#define DK    1536   // inner dim D
#define MROWS 4096   // B*L
#define NOUT  1536   // first GEMM output dim
#define OUTC  23     // second GEMM output dim
#define AFF_SZ (MROWS * 12)
#define HSTRIDE 1544 // bf16 row stride in head LDS (+8 pad)

// round-to-nearest (ties up) fp32 -> bf16 bits
__device__ __forceinline__ unsigned int pkbf(float lo, float hi) {
    unsigned int a = __float_as_uint(lo) + 0x8000u;
    unsigned int b = __float_as_uint(hi) + 0x8000u;
    return (b & 0xffff0000u) | (a >> 16);
}
__device__ __forceinline__ unsigned short f2bf1(float v) {
    return (unsigned short)((__float_as_uint(v) + 0x8000u) >> 16);
}
__device__ __forceinline__ float bflo(unsigned int u) {
    return __uint_as_float(u << 16);
}
__device__ __forceinline__ float bfhi(unsigned int u) {
    return __uint_as_float(u & 0xffff0000u);
}

// async global->LDS, 16B per lane. LDS dest is wave-uniform base;
// HW writes base + lane*16. Global src is per-lane.
__device__ __forceinline__ void async16(const unsigned short* g, unsigned short* l) {
    __builtin_amdgcn_global_load_lds(
        (const __attribute__((address_space(1))) unsigned int*)(g),
        (__attribute__((address_space(3))) unsigned int*)(l), 16, 0, 0);
}

// ===========================================================================
// FAST PATH (needs ~30 MB workspace; harness provides 256 MB)
// R6: explicit LDS dbuf REGRESSED (135.9 -> 141.3) — reverted (m99/m100).
// R7: replay confirmed R5 structure @ 135.4 (noise ±0.5).
// R8 (this): head 16 rows/block — P2 MFMA row-utilization 8/16 -> 16/16.
// ===========================================================================

// ---------------------------------------------------------------------------
// Kernel 0: one-shot fp32 -> bf16 conversion of x, w1, w2 (memory-bound).
// ---------------------------------------------------------------------------
__global__ __launch_bounds__(256)
void convert_kernel(const float* __restrict__ x, const float* __restrict__ w1,
                    const float* __restrict__ w2, unsigned short* __restrict__ xb,
                    unsigned short* __restrict__ w1b, unsigned short* __restrict__ w2b)
{
    const int NX8  = (MROWS * DK) / 8;   // 786432
    const int NW18 = (DK * DK) / 8;      // 294912
    const int NW28 = (OUTC * DK) / 8;    // 4416
    const int TOT  = NX8 + NW18 + NW28;
    for (int i = blockIdx.x * blockDim.x + threadIdx.x; i < TOT;
         i += gridDim.x * blockDim.x) {
        const float* src; unsigned short* dst; int j;
        if (i < NX8)             { src = x;  dst = xb;  j = i; }
        else if (i < NX8 + NW18) { src = w1; dst = w1b; j = i - NX8; }
        else                     { src = w2; dst = w2b; j = i - NX8 - NW18; }
        float4 a = *(const float4*)(src + (size_t)j * 8);
        float4 b = *(const float4*)(src + (size_t)j * 8 + 4);
        uint4 u;
        u.x = pkbf(a.x, a.y); u.y = pkbf(a.z, a.w);
        u.z = pkbf(b.x, b.y); u.w = pkbf(b.z, b.w);
        *(uint4*)(dst + (size_t)j * 8) = u;
    }
}

// ---------------------------------------------------------------------------
// Kernel 1 (fast): Hb = bf16( gelu(xb @ w1b^T + b1) )  [M=4096,N=1536,K=1536]
// 128x96 tile, grid 32x16 = 512 blocks = 2/CU exact (balanced). BK=64,
// 4 waves (2x2), per-wave 64x48 (acc[4][3]). global_load_lds width 16,
// SINGLE LDS buffer, 2 barriers per K-step (best-measured structure, R5/R7).
// Rule-#21 both-sides XOR chunk swizzle:
//   LDS[R][c] = global[R][c ^ (R&7)] (inverse-swizzled per-lane GLOBAL src,
//   linear LDS dest); fragment read fetches chunk q ^ (R&7).
//   Invariants: staging row_local&7 == lane>>3; fragment R&7 == lane15&7.
//   Residual bank aliasing 2-way (free, m136).
// ---------------------------------------------------------------------------
__global__ __launch_bounds__(256, 2)
void gemm1_fast(const unsigned short* __restrict__ A, const unsigned short* __restrict__ Bm,
                const float* __restrict__ b1, unsigned short* __restrict__ Hb)
{
    __shared__ __align__(16) unsigned short As[128 * 64];
    __shared__ __align__(16) unsigned short Bs[96 * 64];

    const int tid    = threadIdx.x;
    const int wave   = tid >> 6;
    const int lane   = tid & 63;
    const int lane15 = lane & 15;
    const int quad   = lane >> 4;
    const int wm     = (wave & 1) * 64;   // M offset of wave tile
    const int wn     = (wave >> 1) * 48;  // N offset of wave tile (48 = 6*8)
    const int sw     = lane15 & 7;        // == R&7 for all fragment rows this lane reads

    const int row0 = blockIdx.x * 128;
    const int col0 = blockIdx.y * 96;

    // staging: one async16 covers 8 rows x 64 cols (64 lanes x 16B).
    // lane l -> row + (l>>3), K-chunk (l&7) ^ (l>>3)  [inverse swizzle].
    const int lr = lane >> 3;
    const int lc = (lane & 7) ^ lr;

    const unsigned short* ga = A  + (size_t)(row0 + wave * 8 + lr) * DK + lc * 8;
    const unsigned short* gb = Bm + (size_t)(col0 + wave * 8 + lr) * DK + lc * 8;

    unsigned short* lasA = &As[(wave * 8) * 64];   // wave-uniform
    unsigned short* lasB = &Bs[(wave * 8) * 64];

    floatx4 acc[4][3] = {};

    for (int k0 = 0; k0 < DK; k0 += 64) {
        #pragma unroll
        for (int i = 0; i < 4; ++i)        // A: 4 waves x 4 calls x 8 rows = 128
            async16(ga + (size_t)(i * 32) * DK + k0, lasA + i * 32 * 64);
        #pragma unroll
        for (int i = 0; i < 3; ++i)        // B: 4 waves x 3 calls x 8 rows = 96
            async16(gb + (size_t)(i * 32) * DK + k0, lasB + i * 32 * 64);
        __syncthreads();   // compiler emits vmcnt(0) drain before s_barrier

        #pragma unroll
        for (int ks = 0; ks < 2; ++ks) {
            bf16x8 af[4], bfr[3];
            #pragma unroll
            for (int mt = 0; mt < 4; ++mt) {
                const int R = wm + mt * 16 + lane15;
                const int q = (ks * 4 + quad) ^ sw;
                af[mt] = *(const bf16x8*)(&As[R * 64 + q * 8]);
            }
            #pragma unroll
            for (int nt = 0; nt < 3; ++nt) {
                const int R = wn + nt * 16 + lane15;
                const int q = (ks * 4 + quad) ^ sw;
                bfr[nt] = *(const bf16x8*)(&Bs[R * 64 + q * 8]);
            }
            #pragma unroll
            for (int mt = 0; mt < 4; ++mt)
                #pragma unroll
                for (int nt = 0; nt < 3; ++nt)
                    acc[mt][nt] = __builtin_amdgcn_mfma_f32_16x16x32_bf16(
                        af[mt], bfr[nt], acc[mt][nt], 0, 0, 0);
        }
        __syncthreads();
    }

    #pragma unroll
    for (int mt = 0; mt < 4; ++mt)
        #pragma unroll
        for (int nt = 0; nt < 3; ++nt)
            #pragma unroll
            for (int r = 0; r < 4; ++r) {
                int row = row0 + wm + mt * 16 + quad * 4 + r;
                int col = col0 + wn + nt * 16 + lane15;
                float v = acc[mt][nt][r] + b1[col];
                v = 0.5f * v * (1.0f + erff(v * 0.70710678118654752f));
                Hb[(size_t)row * NOUT + col] = f2bf1(v);
            }
}

// ---------------------------------------------------------------------------
// Kernel 2 (fast): head, 16 rows/block (256 blocks = 1/CU exact).
// P2 A-fragment row = lane15 (all 16 MFMA rows valid; was lane15&7 with
// half the 16x16 D-tile discarded). Same MFMA count/block, half the blocks.
// LDS: 16*1544*2 + pred + pr + st ~ 53.6 KB.
// ---------------------------------------------------------------------------
__global__ __launch_bounds__(256)
void head_fast(const unsigned short* __restrict__ Hb, const float* __restrict__ ln_g,
               const float* __restrict__ ln_b, const unsigned short* __restrict__ w2b,
               const float* __restrict__ b2, const float* __restrict__ affine,
               const int* __restrict__ amask, float* __restrict__ out)
{
    __shared__ __align__(16) unsigned short hb[16][HSTRIDE];
    __shared__ float st[16][2];
    __shared__ float pred[2][16][17];
    __shared__ float pr[16][32];

    const int tid    = threadIdx.x;
    const int lane   = tid & 63;
    const int wave   = tid >> 6;
    const int lane15 = lane & 15;
    const int quad   = lane >> 4;
    const int row16  = blockIdx.x * 16;

    // -------- P1: 4 rows per wave, stats + stash raw bf16 --------
    #pragma unroll
    for (int rr = 0; rr < 4; ++rr) {
        const int r = wave * 4 + rr;
        const unsigned short* src = Hb + (size_t)(row16 + r) * DK;
        float s = 0.f, ss = 0.f;
        #pragma unroll
        for (int j = 0; j < 3; ++j) {
            const int e8 = lane + 64 * j;            // ushort8 unit 0..191
            uint4 u = *(const uint4*)(src + e8 * 8);
            *(uint4*)(&hb[r][e8 * 8]) = u;
            float f0 = bflo(u.x), f1 = bfhi(u.x), f2 = bflo(u.y), f3 = bfhi(u.y);
            float f4 = bflo(u.z), f5 = bfhi(u.z), f6 = bflo(u.w), f7 = bfhi(u.w);
            s  += ((f0 + f1) + (f2 + f3)) + ((f4 + f5) + (f6 + f7));
            ss += ((f0*f0 + f1*f1) + (f2*f2 + f3*f3)) + ((f4*f4 + f5*f5) + (f6*f6 + f7*f7));
        }
        #pragma unroll
        for (int off = 32; off > 0; off >>= 1) {
            s  += __shfl_down(s, off, 64);
            ss += __shfl_down(ss, off, 64);
        }
        if (lane == 0) {
            float mu  = s * (1.f / DK);
            float var = ss * (1.f / DK) - mu * mu;
            st[r][0] = mu;
            st[r][1] = 1.f / sqrtf(var + 1e-5f);
        }
    }
    __syncthreads();

    // -------- P1b: normalize in place (16 thr/row, 12 ushort8 units each) ----
    {
        const int r   = tid >> 4;
        const int c16 = tid & 15;
        const float mu = st[r][0], rstd = st[r][1];
        const float murstd = mu * rstd;
        #pragma unroll
        for (int jj = 0; jj < 12; ++jj) {
            const int e8 = c16 + 16 * jj;            // ushort8 unit 0..191
            const int d  = e8 * 8;
            uint4 u = *(uint4*)(&hb[r][d]);
            float4 g0 = *(const float4*)(ln_g + d);
            float4 g1 = *(const float4*)(ln_g + d + 4);
            float4 b0 = *(const float4*)(ln_b + d);
            float4 b1v = *(const float4*)(ln_b + d + 4);
            float h0 = fmaf(bflo(u.x), rstd, -murstd), h1 = fmaf(bfhi(u.x), rstd, -murstd);
            float h2 = fmaf(bflo(u.y), rstd, -murstd), h3 = fmaf(bfhi(u.y), rstd, -murstd);
            float h4 = fmaf(bflo(u.z), rstd, -murstd), h5 = fmaf(bfhi(u.z), rstd, -murstd);
            float h6 = fmaf(bflo(u.w), rstd, -murstd), h7 = fmaf(bfhi(u.w), rstd, -murstd);
            h0 = fmaf(h0, g0.x, b0.x);  h1 = fmaf(h1, g0.y, b0.y);
            h2 = fmaf(h2, g0.z, b0.z);  h3 = fmaf(h3, g0.w, b0.w);
            h4 = fmaf(h4, g1.x, b1v.x); h5 = fmaf(h5, g1.y, b1v.y);
            h6 = fmaf(h6, g1.z, b1v.z); h7 = fmaf(h7, g1.w, b1v.w);
            u.x = pkbf(h0, h1); u.y = pkbf(h2, h3);
            u.z = pkbf(h4, h5); u.w = pkbf(h6, h7);
            *(uint4*)(&hb[r][d]) = u;
        }
    }
    __syncthreads();

    // -------- P2: p = h_ln @ w2^T via MFMA, all 16 rows valid --------
    {
        const int ntile = wave & 1;
        const int khalf = wave >> 1;
        const int o     = ntile * 16 + lane15;
        const int osafe = (o < OUTC) ? o : 0;
        const unsigned short* wrow = w2b + (size_t)osafe * DK;
        const int mrow  = lane15;            // full 16 A-rows (was lane15&7)

        floatx4 acc = {0.f, 0.f, 0.f, 0.f};
        #pragma unroll 4
        for (int kk = 0; kk < 24; ++kk) {
            const int kb = khalf * 768 + kk * 32 + quad * 8;
            bf16x8 afr = *(const bf16x8*)(&hb[mrow][kb]);
            bf16x8 bfr = *(const bf16x8*)(wrow + kb);
            acc = __builtin_amdgcn_mfma_f32_16x16x32_bf16(afr, bfr, acc, 0, 0, 0);
        }

        if (khalf == 1) {
            #pragma unroll
            for (int r2 = 0; r2 < 4; ++r2)
                pred[ntile][quad * 4 + r2][lane15] = acc[r2];
        }
        __syncthreads();
        if (khalf == 0) {
            #pragma unroll
            for (int r2 = 0; r2 < 4; ++r2) {
                const int row = quad * 4 + r2;      // 0..15, all valid
                if (o < OUTC)
                    pr[row][o] = acc[r2] + pred[ntile][row][lane15] + b2[o];
            }
        }
    }
    __syncthreads();

    // -------- P3: geometry, one row per thread --------
    if (tid < 16) {
        const int row = row16 + tid;
        float p[OUTC];
        #pragma unroll
        for (int oo = 0; oo < OUTC; ++oo) p[oo] = pr[tid][oo];

        float trans[3] = { p[0] * 10.f, p[1] * 10.f, p[2] * 10.f };
        float xv[3] = { p[3], p[4], p[5] };
        float yv[3] = { p[6], p[7], p[8] };
        float xn = sqrtf(xv[0]*xv[0] + xv[1]*xv[1] + xv[2]*xv[2]) + 1e-5f;
        xv[0] /= xn; xv[1] /= xn; xv[2] /= xn;
        float yn = sqrtf(yv[0]*yv[0] + yv[1]*yv[1] + yv[2]*yv[2]) + 1e-5f;
        yv[0] /= yn; yv[1] /= yn; yv[2] /= yn;

        float a0 = -xv[0], a1 = -xv[1], a2 = -xv[2];
        float inv = 1.f / sqrtf(a0*a0 + a1*a1 + a2*a2 + 1e-12f);
        float e0x = a0 * inv, e0y = a1 * inv, e0z = a2 * inv;
        float c = e0x*yv[0] + e0y*yv[1] + e0z*yv[2];
        float e1x = yv[0] - e0x * c, e1y = yv[1] - e0y * c, e1z = yv[2] - e0z * c;
        inv = 1.f / sqrtf(e1x*e1x + e1y*e1y + e1z*e1z + 1e-12f);
        e1x *= inv; e1y *= inv; e1z *= inv;
        float e2x = e0y*e1z - e0z*e1y;
        float e2y = e0z*e1x - e0x*e1z;
        float e2z = e0x*e1y - e0y*e1x;

        float Ru[3][3] = { { e0x, e1x, e2x },
                           { e0y, e1y, e2y },
                           { e0z, e1z, e2z } };
        float tu[3] = { trans[0], trans[1], trans[2] };
        if (amask[row] == 0) {
            Ru[0][0]=1.f; Ru[0][1]=0.f; Ru[0][2]=0.f;
            Ru[1][0]=0.f; Ru[1][1]=1.f; Ru[1][2]=0.f;
            Ru[2][0]=0.f; Ru[2][1]=0.f; Ru[2][2]=1.f;
            tu[0]=tu[1]=tu[2]=0.f;
        }

        const float* af = affine + (size_t)row * 12;
        float R0[3][3] = { { af[0], af[1], af[2] },
                           { af[3], af[4], af[5] },
                           { af[6], af[7], af[8] } };
        float t0[3] = { af[9], af[10], af[11] };

        float R[3][3], t[3];
        #pragma unroll
        for (int i = 0; i < 3; ++i) {
            #pragma unroll
            for (int j = 0; j < 3; ++j)
                R[i][j] = R0[i][0]*Ru[0][j] + R0[i][1]*Ru[1][j] + R0[i][2]*Ru[2][j];
            t[i] = R0[i][0]*tu[0] + R0[i][1]*tu[1] + R0[i][2]*tu[2] + t0[i];
        }

        float* oa = out + (size_t)row * 12;
        #pragma unroll
        for (int i = 0; i < 3; ++i) {
            #pragma unroll
            for (int j = 0; j < 3; ++j) oa[i*3 + j] = R[i][j];
            oa[9 + i] = t[i];
        }

        const float BB[3][3] = { { -0.525f, 1.363f, 0.f },
                                 {  0.f,    0.f,   0.f },
                                 {  1.526f, 0.f,   0.f } };
        float* op = out + AFF_SZ + (size_t)row * 9;
        #pragma unroll
        for (int a = 0; a < 3; ++a)
            #pragma unroll
            for (int i = 0; i < 3; ++i)
                op[a*3 + i] = R[i][0]*BB[a][0] + R[i][1]*BB[a][1] + R[i][2]*BB[a][2] + t[i];
    }
}

// ===========================================================================
// LEGACY PATH — verbatim structure of the harness-verified 149 µs kernel.
// Used only when ws_size cannot hold the pre-converted operands.
// ===========================================================================

__global__ __launch_bounds__(256, 2)
void gemm1_legacy(const float* __restrict__ A, const float* __restrict__ Bm,
                  const float* __restrict__ b1, unsigned short* __restrict__ Hb)
{
    __shared__ __align__(16) unsigned short As[128][72];
    __shared__ __align__(16) unsigned short Bs[128][72];

    const int tid    = threadIdx.x;
    const int wave   = tid >> 6;
    const int lane   = tid & 63;
    const int wm     = (wave & 1) * 64;
    const int wn     = (wave >> 1) * 64;
    const int lane15 = lane & 15;
    const int quad   = lane >> 4;

    const int row0 = blockIdx.x * 128;
    const int col0 = blockIdx.y * 128;

    const int rbase = tid >> 4;
    const int c4    = (tid & 15) << 2;

    const float* Ab = A  + (size_t)(row0 + rbase) * DK + c4;
    const float* Bb = Bm + (size_t)(col0 + rbase) * DK + c4;

    floatx4 acc[4][4] = {};
    float4 pa[8], pb[8];

    #pragma unroll
    for (int i = 0; i < 8; ++i) {
        pa[i] = *(const float4*)(Ab + (size_t)(16 * i) * DK);
        pb[i] = *(const float4*)(Bb + (size_t)(16 * i) * DK);
    }

    for (int k0 = 0; k0 < DK; k0 += 64) {
        #pragma unroll
        for (int i = 0; i < 8; ++i) {
            unsigned int lo = pkbf(pa[i].x, pa[i].y);
            unsigned int hi = pkbf(pa[i].z, pa[i].w);
            *(uint2*)(&As[rbase + 16 * i][c4]) = make_uint2(lo, hi);
            lo = pkbf(pb[i].x, pb[i].y);
            hi = pkbf(pb[i].z, pb[i].w);
            *(uint2*)(&Bs[rbase + 16 * i][c4]) = make_uint2(lo, hi);
        }
        if (k0 + 64 < DK) {
            #pragma unroll
            for (int i = 0; i < 8; ++i) {
                pa[i] = *(const float4*)(Ab + (size_t)(16 * i) * DK + k0 + 64);
                pb[i] = *(const float4*)(Bb + (size_t)(16 * i) * DK + k0 + 64);
            }
        }
        __syncthreads();

        #pragma unroll
        for (int ks = 0; ks < 2; ++ks) {
            bf16x8 af[4], bfr[4];
            #pragma unroll
            for (int mt = 0; mt < 4; ++mt)
                af[mt] = *(const bf16x8*)(&As[wm + mt * 16 + lane15][ks * 32 + quad * 8]);
            #pragma unroll
            for (int nt = 0; nt < 4; ++nt)
                bfr[nt] = *(const bf16x8*)(&Bs[wn + nt * 16 + lane15][ks * 32 + quad * 8]);
            #pragma unroll
            for (int mt = 0; mt < 4; ++mt)
                #pragma unroll
                for (int nt = 0; nt < 4; ++nt)
                    acc[mt][nt] = __builtin_amdgcn_mfma_f32_16x16x32_bf16(
                        af[mt], bfr[nt], acc[mt][nt], 0, 0, 0);
        }
        __syncthreads();
    }

    #pragma unroll
    for (int mt = 0; mt < 4; ++mt)
        #pragma unroll
        for (int nt = 0; nt < 4; ++nt)
            #pragma unroll
            for (int r = 0; r < 4; ++r) {
                int row = row0 + wm + mt * 16 + quad * 4 + r;
                int col = col0 + wn + nt * 16 + lane15;
                float v = acc[mt][nt][r] + b1[col];
                v = 0.5f * v * (1.0f + erff(v * 0.70710678118654752f));
                Hb[(size_t)row * NOUT + col] = f2bf1(v);
            }
}

__global__ __launch_bounds__(256)
void head_legacy(const unsigned short* __restrict__ Hb, const float* __restrict__ ln_g,
                 const float* __restrict__ ln_b, const float* __restrict__ w2,
                 const float* __restrict__ b2, const float* __restrict__ affine,
                 const int* __restrict__ amask, float* __restrict__ out)
{
    __shared__ __align__(16) unsigned short hb[8][HSTRIDE];
    __shared__ float st[8][2];
    __shared__ float pred[2][16][17];
    __shared__ float pr[8][32];

    const int tid    = threadIdx.x;
    const int lane   = tid & 63;
    const int wave   = tid >> 6;
    const int lane15 = lane & 15;
    const int quad   = lane >> 4;
    const int row8   = blockIdx.x * 8;

    #pragma unroll
    for (int rr = 0; rr < 2; ++rr) {
        const int r = wave * 2 + rr;
        const unsigned short* src = Hb + (size_t)(row8 + r) * DK;
        float s = 0.f, ss = 0.f;
        #pragma unroll
        for (int j = 0; j < 3; ++j) {
            const int e8 = lane + 64 * j;
            uint4 u = *(const uint4*)(src + e8 * 8);
            *(uint4*)(&hb[r][e8 * 8]) = u;
            float f0 = bflo(u.x), f1 = bfhi(u.x), f2 = bflo(u.y), f3 = bfhi(u.y);
            float f4 = bflo(u.z), f5 = bfhi(u.z), f6 = bflo(u.w), f7 = bfhi(u.w);
            s  += ((f0 + f1) + (f2 + f3)) + ((f4 + f5) + (f6 + f7));
            ss += ((f0*f0 + f1*f1) + (f2*f2 + f3*f3)) + ((f4*f4 + f5*f5) + (f6*f6 + f7*f7));
        }
        #pragma unroll
        for (int off = 32; off > 0; off >>= 1) {
            s  += __shfl_down(s, off, 64);
            ss += __shfl_down(ss, off, 64);
        }
        if (lane == 0) {
            float mu  = s * (1.f / DK);
            float var = ss * (1.f / DK) - mu * mu;
            st[r][0] = mu;
            st[r][1] = 1.f / sqrtf(var + 1e-5f);
        }
    }
    __syncthreads();

    {
        const int r   = tid >> 5;
        const int c32 = tid & 31;
        const float mu = st[r][0], rstd = st[r][1];
        const float murstd = mu * rstd;
        #pragma unroll
        for (int jj = 0; jj < 6; ++jj) {
            const int e8 = c32 + 32 * jj;
            const int d  = e8 * 8;
            uint4 u = *(uint4*)(&hb[r][d]);
            float4 g0 = *(const float4*)(ln_g + d);
            float4 g1 = *(const float4*)(ln_g + d + 4);
            float4 b0 = *(const float4*)(ln_b + d);
            float4 b1v = *(const float4*)(ln_b + d + 4);
            float h0 = fmaf(bflo(u.x), rstd, -murstd), h1 = fmaf(bfhi(u.x), rstd, -murstd);
            float h2 = fmaf(bflo(u.y), rstd, -murstd), h3 = fmaf(bfhi(u.y), rstd, -murstd);
            float h4 = fmaf(bflo(u.z), rstd, -murstd), h5 = fmaf(bfhi(u.z), rstd, -murstd);
            float h6 = fmaf(bflo(u.w), rstd, -murstd), h7 = fmaf(bfhi(u.w), rstd, -murstd);
            h0 = fmaf(h0, g0.x, b0.x);  h1 = fmaf(h1, g0.y, b0.y);
            h2 = fmaf(h2, g0.z, b0.z);  h3 = fmaf(h3, g0.w, b0.w);
            h4 = fmaf(h4, g1.x, b1v.x); h5 = fmaf(h5, g1.y, b1v.y);
            h6 = fmaf(h6, g1.z, b1v.z); h7 = fmaf(h7, g1.w, b1v.w);
            u.x = pkbf(h0, h1); u.y = pkbf(h2, h3);
            u.z = pkbf(h4, h5); u.w = pkbf(h6, h7);
            *(uint4*)(&hb[r][d]) = u;
        }
    }
    __syncthreads();

    {
        const int ntile = wave & 1;
        const int khalf = wave >> 1;
        const int o     = ntile * 16 + lane15;
        const int osafe = (o < OUTC) ? o : 0;
        const float* wrow = w2 + (size_t)osafe * DK;
        const int mrow  = lane15 & 7;

        floatx4 acc = {0.f, 0.f, 0.f, 0.f};
        #pragma unroll 4
        for (int kk = 0; kk < 24; ++kk) {
            const int kb = khalf * 768 + kk * 32 + quad * 8;
            bf16x8 afr = *(const bf16x8*)(&hb[mrow][kb]);
            float4 wa = *(const float4*)(wrow + kb);
            float4 wb = *(const float4*)(wrow + kb + 4);
            union { unsigned int u[4]; bf16x8 v; } bu;
            bu.u[0] = pkbf(wa.x, wa.y);
            bu.u[1] = pkbf(wa.z, wa.w);
            bu.u[2] = pkbf(wb.x, wb.y);
            bu.u[3] = pkbf(wb.z, wb.w);
            acc = __builtin_amdgcn_mfma_f32_16x16x32_bf16(afr, bu.v, acc, 0, 0, 0);
        }

        if (khalf == 1) {
            #pragma unroll
            for (int r2 = 0; r2 < 4; ++r2)
                pred[ntile][quad * 4 + r2][lane15] = acc[r2];
        }
        __syncthreads();
        if (khalf == 0) {
            #pragma unroll
            for (int r2 = 0; r2 < 4; ++r2) {
                const int row = quad * 4 + r2;
                if (row < 8 && o < OUTC)
                    pr[row][o] = acc[r2] + pred[ntile][row][lane15] + b2[o];
            }
        }
    }
    __syncthreads();

    if (tid < 8) {
        const int row = row8 + tid;
        float p[OUTC];
        #pragma unroll
        for (int oo = 0; oo < OUTC; ++oo) p[oo] = pr[tid][oo];

        float trans[3] = { p[0] * 10.f, p[1] * 10.f, p[2] * 10.f };
        float xv[3] = { p[3], p[4], p[5] };
        float yv[3] = { p[6], p[7], p[8] };
        float xn = sqrtf(xv[0]*xv[0] + xv[1]*xv[1] + xv[2]*xv[2]) + 1e-5f;
        xv[0] /= xn; xv[1] /= xn; xv[2] /= xn;
        float yn = sqrtf(yv[0]*yv[0] + yv[1]*yv[1] + yv[2]*yv[2]) + 1e-5f;
        yv[0] /= yn; yv[1] /= yn; yv[2] /= yn;

        float a0 = -xv[0], a1 = -xv[1], a2 = -xv[2];
        float inv = 1.f / sqrtf(a0*a0 + a1*a1 + a2*a2 + 1e-12f);
        float e0x = a0 * inv, e0y = a1 * inv, e0z = a2 * inv;
        float c = e0x*yv[0] + e0y*yv[1] + e0z*yv[2];
        float e1x = yv[0] - e0x * c, e1y = yv[1] - e0y * c, e1z = yv[2] - e0z * c;
        inv = 1.f / sqrtf(e1x*e1x + e1y*e1y + e1z*e1z + 1e-12f);
        e1x *= inv; e1y *= inv; e1z *= inv;
        float e2x = e0y*e1z - e0z*e1y;
        float e2y = e0z*e1x - e0x*e1z;
        float e2z = e0x*e1y - e0y*e1x;

        float Ru[3][3] = { { e0x, e1x, e2x },
                           { e0y, e1y, e2y },
                           { e0z, e1z, e2z } };
        float tu[3] = { trans[0], trans[1], trans[2] };
        if (amask[row] == 0) {
            Ru[0][0]=1.f; Ru[0][1]=0.f; Ru[0][2]=0.f;
            Ru[1][0]=0.f; Ru[1][1]=1.f; Ru[1][2]=0.f;
            Ru[2][0]=0.f; Ru[2][1]=0.f; Ru[2][2]=1.f;
            tu[0]=tu[1]=tu[2]=0.f;
        }

        const float* af = affine + (size_t)row * 12;
        float R0[3][3] = { { af[0], af[1], af[2] },
                           { af[3], af[4], af[5] },
                           { af[6], af[7], af[8] } };
        float t0[3] = { af[9], af[10], af[11] };

        float R[3][3], t[3];
        #pragma unroll
        for (int i = 0; i < 3; ++i) {
            #pragma unroll
            for (int j = 0; j < 3; ++j)
                R[i][j] = R0[i][0]*Ru[0][j] + R0[i][1]*Ru[1][j] + R0[i][2]*Ru[2][j];
            t[i] = R0[i][0]*tu[0] + R0[i][1]*tu[1] + R0[i][2]*tu[2] + t0[i];
        }

        float* oa = out + (size_t)row * 12;
        #pragma unroll
        for (int i = 0; i < 3; ++i) {
            #pragma unroll
            for (int j = 0; j < 3; ++j) oa[i*3 + j] = R[i][j];
            oa[9 + i] = t[i];
        }

        const float BB[3][3] = { { -0.525f, 1.363f, 0.f },
                                 {  0.f,    0.f,   0.f },
                                 {  1.526f, 0.f,   0.f } };
        float* op = out + AFF_SZ + (size_t)row * 9;
        #pragma unroll
        for (int a = 0; a < 3; ++a)
            #pragma unroll
            for (int i = 0; i < 3; ++i)
                op[a*3 + i] = R[i][0]*BB[a][0] + R[i][1]*BB[a][1] + R[i][2]*BB[a][2] + t[i];
    }
}

extern "C" void kernel_launch(void* const* d_in, const int* in_sizes, int n_in,
                              void* d_out, int out_size, void* d_ws, size_t ws_size,
                              hipStream_t stream) {
    const float* x      = (const float*)d_in[0];
    const float* affine = (const float*)d_in[1];
    const int*   amask  = (const int*)  d_in[2];
    const float* w1     = (const float*)d_in[3];
    const float* b1     = (const float*)d_in[4];
    const float* ln_g   = (const float*)d_in[5];
    const float* ln_b   = (const float*)d_in[6];
    const float* w2     = (const float*)d_in[7];
    const float* b2     = (const float*)d_in[8];
    float* out = (float*)d_out;

    const size_t HB_ELEMS  = (size_t)MROWS * DK;     // 6.29 M
    const size_t W1_ELEMS  = (size_t)DK * DK;        // 2.36 M
    const size_t W2_ELEMS  = (size_t)OUTC * DK;      // 35 K
    const size_t FAST_BYTES = (2 * HB_ELEMS + W1_ELEMS + W2_ELEMS) * sizeof(unsigned short);

    unsigned short* Hb = (unsigned short*)d_ws;

    if (ws_size >= FAST_BYTES) {
        // workspace layout (bf16): Hb | xb | w1b | w2b  (~30 MB)
        unsigned short* xb  = Hb  + HB_ELEMS;
        unsigned short* w1b = xb  + HB_ELEMS;
        unsigned short* w2b = w1b + W1_ELEMS;

        convert_kernel<<<2048, 256, 0, stream>>>(x, w1, w2, xb, w1b, w2b);
        dim3 g1f(MROWS / 128, NOUT / 96);   // 32 x 16 = 512 blocks = 2/CU exact
        gemm1_fast<<<g1f, 256, 0, stream>>>(xb, w1b, b1, Hb);
        head_fast<<<MROWS / 16, 256, 0, stream>>>(Hb, ln_g, ln_b, w2b, b2, affine, amask, out);
    } else {
        // known-good 149 µs path (workspace = Hb only, 12.6 MB)
        dim3 g1(MROWS / 128, NOUT / 128);   // 32 x 12 = 384 blocks
        gemm1_legacy<<<g1, 256, 0, stream>>>(x, w1, b1, Hb);
        head_legacy<<<MROWS / 8, 256, 0, stream>>>(Hb, ln_g, ln_b, w2, b2, affine, amask, out);
    }
}

// Round 9
// 135.949 us; speedup vs baseline: 1.0053x; 1.0053x over previous
//
#include <hip/hip_runtime.h>
#include <hip/hip_bf16.h>
#include <math.h>

typedef __bf16 bf16x8 __attribute__((ext_vector_type(8)));
typedef float floatx4 __attribute__((ext_vector_type(4)));

#define DK    1536   // inner dim D
#define MROWS 4096   // B*L
#define NOUT  1536   // first GEMM output dim
#define OUTC  23     // second GEMM output dim
#define AFF_SZ (MROWS * 12)
#define HSTRIDE 1544 // bf16 row stride in head LDS (+8 pad)

// round-to-nearest (ties up) fp32 -> bf16 bits
__device__ __forceinline__ unsigned int pkbf(float lo, float hi) {
    unsigned int a = __float_as_uint(lo) + 0x8000u;
    unsigned int b = __float_as_uint(hi) + 0x8000u;
    return (b & 0xffff0000u) | (a >> 16);
}
__device__ __forceinline__ unsigned short f2bf1(float v) {
    return (unsigned short)((__float_as_uint(v) + 0x8000u) >> 16);
}
__device__ __forceinline__ float bflo(unsigned int u) {
    return __uint_as_float(u << 16);
}
__device__ __forceinline__ float bfhi(unsigned int u) {
    return __uint_as_float(u & 0xffff0000u);
}

// async global->LDS, 16B per lane. LDS dest is wave-uniform base;
// HW writes base + lane*16. Global src is per-lane.
__device__ __forceinline__ void async16(const unsigned short* g, unsigned short* l) {
    __builtin_amdgcn_global_load_lds(
        (const __attribute__((address_space(1))) unsigned int*)(g),
        (__attribute__((address_space(3))) unsigned int*)(l), 16, 0, 0);
}

// ===========================================================================
// FAST PATH — best-measured configuration (R7: 135.37 µs, vs 149.0 baseline).
// Ledger: R0 pre-convert+gload_lds −10.3 · R4 regrid 128x96 −2.9 ·
// R6 LDS dbuf +5.4 (REVERTED, confirms m99/m100) · R8 head-16row +1.3
// (REVERTED: head P2 MFMA was never significant; 1/CU lost TLP).
// ===========================================================================

// ---------------------------------------------------------------------------
// Kernel 0: one-shot fp32 -> bf16 conversion of x, w1, w2 (memory-bound,
// ~75 MB traffic ~ 10 µs, at BW roofline).
// ---------------------------------------------------------------------------
__global__ __launch_bounds__(256)
void convert_kernel(const float* __restrict__ x, const float* __restrict__ w1,
                    const float* __restrict__ w2, unsigned short* __restrict__ xb,
                    unsigned short* __restrict__ w1b, unsigned short* __restrict__ w2b)
{
    const int NX8  = (MROWS * DK) / 8;   // 786432
    const int NW18 = (DK * DK) / 8;      // 294912
    const int NW28 = (OUTC * DK) / 8;    // 4416
    const int TOT  = NX8 + NW18 + NW28;
    for (int i = blockIdx.x * blockDim.x + threadIdx.x; i < TOT;
         i += gridDim.x * blockDim.x) {
        const float* src; unsigned short* dst; int j;
        if (i < NX8)             { src = x;  dst = xb;  j = i; }
        else if (i < NX8 + NW18) { src = w1; dst = w1b; j = i - NX8; }
        else                     { src = w2; dst = w2b; j = i - NX8 - NW18; }
        float4 a = *(const float4*)(src + (size_t)j * 8);
        float4 b = *(const float4*)(src + (size_t)j * 8 + 4);
        uint4 u;
        u.x = pkbf(a.x, a.y); u.y = pkbf(a.z, a.w);
        u.z = pkbf(b.x, b.y); u.w = pkbf(b.z, b.w);
        *(uint4*)(dst + (size_t)j * 8) = u;
    }
}

// ---------------------------------------------------------------------------
// Kernel 1 (fast): Hb = bf16( gelu(xb @ w1b^T + b1) )  [M=4096,N=1536,K=1536]
// 128x96 tile, grid 32x16 = 512 blocks = 2/CU exact (balanced). BK=64,
// 4 waves (2x2), per-wave 64x48 (acc[4][3]). global_load_lds width 16,
// SINGLE LDS buffer, 2 barriers per K-step (best-measured; explicit dbuf
// regressed +5.4 µs — implicit 2-block/CU overlap already hides staging).
// Rule-#21 both-sides XOR chunk swizzle:
//   LDS[R][c] = global[R][c ^ (R&7)] (inverse-swizzled per-lane GLOBAL src,
//   linear LDS dest); fragment read fetches chunk q ^ (R&7).
//   Invariants: staging row_local&7 == lane>>3; fragment R&7 == lane15&7.
//   Residual bank aliasing 2-way (free, m136).
// ---------------------------------------------------------------------------
__global__ __launch_bounds__(256, 2)
void gemm1_fast(const unsigned short* __restrict__ A, const unsigned short* __restrict__ Bm,
                const float* __restrict__ b1, unsigned short* __restrict__ Hb)
{
    __shared__ __align__(16) unsigned short As[128 * 64];
    __shared__ __align__(16) unsigned short Bs[96 * 64];

    const int tid    = threadIdx.x;
    const int wave   = tid >> 6;
    const int lane   = tid & 63;
    const int lane15 = lane & 15;
    const int quad   = lane >> 4;
    const int wm     = (wave & 1) * 64;   // M offset of wave tile
    const int wn     = (wave >> 1) * 48;  // N offset of wave tile (48 = 6*8)
    const int sw     = lane15 & 7;        // == R&7 for all fragment rows this lane reads

    const int row0 = blockIdx.x * 128;
    const int col0 = blockIdx.y * 96;

    // staging: one async16 covers 8 rows x 64 cols (64 lanes x 16B).
    // lane l -> row + (l>>3), K-chunk (l&7) ^ (l>>3)  [inverse swizzle].
    const int lr = lane >> 3;
    const int lc = (lane & 7) ^ lr;

    const unsigned short* ga = A  + (size_t)(row0 + wave * 8 + lr) * DK + lc * 8;
    const unsigned short* gb = Bm + (size_t)(col0 + wave * 8 + lr) * DK + lc * 8;

    unsigned short* lasA = &As[(wave * 8) * 64];   // wave-uniform
    unsigned short* lasB = &Bs[(wave * 8) * 64];

    floatx4 acc[4][3] = {};

    for (int k0 = 0; k0 < DK; k0 += 64) {
        #pragma unroll
        for (int i = 0; i < 4; ++i)        // A: 4 waves x 4 calls x 8 rows = 128
            async16(ga + (size_t)(i * 32) * DK + k0, lasA + i * 32 * 64);
        #pragma unroll
        for (int i = 0; i < 3; ++i)        // B: 4 waves x 3 calls x 8 rows = 96
            async16(gb + (size_t)(i * 32) * DK + k0, lasB + i * 32 * 64);
        __syncthreads();   // compiler emits vmcnt(0) drain before s_barrier

        #pragma unroll
        for (int ks = 0; ks < 2; ++ks) {
            bf16x8 af[4], bfr[3];
            #pragma unroll
            for (int mt = 0; mt < 4; ++mt) {
                const int R = wm + mt * 16 + lane15;
                const int q = (ks * 4 + quad) ^ sw;
                af[mt] = *(const bf16x8*)(&As[R * 64 + q * 8]);
            }
            #pragma unroll
            for (int nt = 0; nt < 3; ++nt) {
                const int R = wn + nt * 16 + lane15;
                const int q = (ks * 4 + quad) ^ sw;
                bfr[nt] = *(const bf16x8*)(&Bs[R * 64 + q * 8]);
            }
            #pragma unroll
            for (int mt = 0; mt < 4; ++mt)
                #pragma unroll
                for (int nt = 0; nt < 3; ++nt)
                    acc[mt][nt] = __builtin_amdgcn_mfma_f32_16x16x32_bf16(
                        af[mt], bfr[nt], acc[mt][nt], 0, 0, 0);
        }
        __syncthreads();
    }

    #pragma unroll
    for (int mt = 0; mt < 4; ++mt)
        #pragma unroll
        for (int nt = 0; nt < 3; ++nt)
            #pragma unroll
            for (int r = 0; r < 4; ++r) {
                int row = row0 + wm + mt * 16 + quad * 4 + r;
                int col = col0 + wn + nt * 16 + lane15;
                float v = acc[mt][nt][r] + b1[col];
                v = 0.5f * v * (1.0f + erff(v * 0.70710678118654752f));
                Hb[(size_t)row * NOUT + col] = f2bf1(v);
            }
}

// ---------------------------------------------------------------------------
// Kernel 2 (fast): head, 8 rows/block (512 blocks, 2/CU) — R7 best-measured.
// (16-rows variant measured +1.3 µs: P2 MFMA was not the bottleneck and
// 1/CU halved TLP.)
// ---------------------------------------------------------------------------
__global__ __launch_bounds__(256)
void head_fast(const unsigned short* __restrict__ Hb, const float* __restrict__ ln_g,
               const float* __restrict__ ln_b, const unsigned short* __restrict__ w2b,
               const float* __restrict__ b2, const float* __restrict__ affine,
               const int* __restrict__ amask, float* __restrict__ out)
{
    __shared__ __align__(16) unsigned short hb[8][HSTRIDE];
    __shared__ float st[8][2];
    __shared__ float pred[2][16][17];
    __shared__ float pr[8][32];

    const int tid    = threadIdx.x;
    const int lane   = tid & 63;
    const int wave   = tid >> 6;
    const int lane15 = lane & 15;
    const int quad   = lane >> 4;
    const int row8   = blockIdx.x * 8;

    #pragma unroll
    for (int rr = 0; rr < 2; ++rr) {
        const int r = wave * 2 + rr;
        const unsigned short* src = Hb + (size_t)(row8 + r) * DK;
        float s = 0.f, ss = 0.f;
        #pragma unroll
        for (int j = 0; j < 3; ++j) {
            const int e8 = lane + 64 * j;
            uint4 u = *(const uint4*)(src + e8 * 8);
            *(uint4*)(&hb[r][e8 * 8]) = u;
            float f0 = bflo(u.x), f1 = bfhi(u.x), f2 = bflo(u.y), f3 = bfhi(u.y);
            float f4 = bflo(u.z), f5 = bfhi(u.z), f6 = bflo(u.w), f7 = bfhi(u.w);
            s  += ((f0 + f1) + (f2 + f3)) + ((f4 + f5) + (f6 + f7));
            ss += ((f0*f0 + f1*f1) + (f2*f2 + f3*f3)) + ((f4*f4 + f5*f5) + (f6*f6 + f7*f7));
        }
        #pragma unroll
        for (int off = 32; off > 0; off >>= 1) {
            s  += __shfl_down(s, off, 64);
            ss += __shfl_down(ss, off, 64);
        }
        if (lane == 0) {
            float mu  = s * (1.f / DK);
            float var = ss * (1.f / DK) - mu * mu;
            st[r][0] = mu;
            st[r][1] = 1.f / sqrtf(var + 1e-5f);
        }
    }
    __syncthreads();

    {
        const int r   = tid >> 5;
        const int c32 = tid & 31;
        const float mu = st[r][0], rstd = st[r][1];
        const float murstd = mu * rstd;
        #pragma unroll
        for (int jj = 0; jj < 6; ++jj) {
            const int e8 = c32 + 32 * jj;
            const int d  = e8 * 8;
            uint4 u = *(uint4*)(&hb[r][d]);
            float4 g0 = *(const float4*)(ln_g + d);
            float4 g1 = *(const float4*)(ln_g + d + 4);
            float4 b0 = *(const float4*)(ln_b + d);
            float4 b1v = *(const float4*)(ln_b + d + 4);
            float h0 = fmaf(bflo(u.x), rstd, -murstd), h1 = fmaf(bfhi(u.x), rstd, -murstd);
            float h2 = fmaf(bflo(u.y), rstd, -murstd), h3 = fmaf(bfhi(u.y), rstd, -murstd);
            float h4 = fmaf(bflo(u.z), rstd, -murstd), h5 = fmaf(bfhi(u.z), rstd, -murstd);
            float h6 = fmaf(bflo(u.w), rstd, -murstd), h7 = fmaf(bfhi(u.w), rstd, -murstd);
            h0 = fmaf(h0, g0.x, b0.x);  h1 = fmaf(h1, g0.y, b0.y);
            h2 = fmaf(h2, g0.z, b0.z);  h3 = fmaf(h3, g0.w, b0.w);
            h4 = fmaf(h4, g1.x, b1v.x); h5 = fmaf(h5, g1.y, b1v.y);
            h6 = fmaf(h6, g1.z, b1v.z); h7 = fmaf(h7, g1.w, b1v.w);
            u.x = pkbf(h0, h1); u.y = pkbf(h2, h3);
            u.z = pkbf(h4, h5); u.w = pkbf(h6, h7);
            *(uint4*)(&hb[r][d]) = u;
        }
    }
    __syncthreads();

    {
        const int ntile = wave & 1;
        const int khalf = wave >> 1;
        const int o     = ntile * 16 + lane15;
        const int osafe = (o < OUTC) ? o : 0;
        const unsigned short* wrow = w2b + (size_t)osafe * DK;
        const int mrow  = lane15 & 7;

        floatx4 acc = {0.f, 0.f, 0.f, 0.f};
        #pragma unroll 4
        for (int kk = 0; kk < 24; ++kk) {
            const int kb = khalf * 768 + kk * 32 + quad * 8;
            bf16x8 afr = *(const bf16x8*)(&hb[mrow][kb]);
            bf16x8 bfr = *(const bf16x8*)(wrow + kb);
            acc = __builtin_amdgcn_mfma_f32_16x16x32_bf16(afr, bfr, acc, 0, 0, 0);
        }

        if (khalf == 1) {
            #pragma unroll
            for (int r2 = 0; r2 < 4; ++r2)
                pred[ntile][quad * 4 + r2][lane15] = acc[r2];
        }
        __syncthreads();
        if (khalf == 0) {
            #pragma unroll
            for (int r2 = 0; r2 < 4; ++r2) {
                const int row = quad * 4 + r2;
                if (row < 8 && o < OUTC)
                    pr[row][o] = acc[r2] + pred[ntile][row][lane15] + b2[o];
            }
        }
    }
    __syncthreads();

    if (tid < 8) {
        const int row = row8 + tid;
        float p[OUTC];
        #pragma unroll
        for (int oo = 0; oo < OUTC; ++oo) p[oo] = pr[tid][oo];

        float trans[3] = { p[0] * 10.f, p[1] * 10.f, p[2] * 10.f };
        float xv[3] = { p[3], p[4], p[5] };
        float yv[3] = { p[6], p[7], p[8] };
        float xn = sqrtf(xv[0]*xv[0] + xv[1]*xv[1] + xv[2]*xv[2]) + 1e-5f;
        xv[0] /= xn; xv[1] /= xn; xv[2] /= xn;
        float yn = sqrtf(yv[0]*yv[0] + yv[1]*yv[1] + yv[2]*yv[2]) + 1e-5f;
        yv[0] /= yn; yv[1] /= yn; yv[2] /= yn;

        float a0 = -xv[0], a1 = -xv[1], a2 = -xv[2];
        float inv = 1.f / sqrtf(a0*a0 + a1*a1 + a2*a2 + 1e-12f);
        float e0x = a0 * inv, e0y = a1 * inv, e0z = a2 * inv;
        float c = e0x*yv[0] + e0y*yv[1] + e0z*yv[2];
        float e1x = yv[0] - e0x * c, e1y = yv[1] - e0y * c, e1z = yv[2] - e0z * c;
        inv = 1.f / sqrtf(e1x*e1x + e1y*e1y + e1z*e1z + 1e-12f);
        e1x *= inv; e1y *= inv; e1z *= inv;
        float e2x = e0y*e1z - e0z*e1y;
        float e2y = e0z*e1x - e0x*e1z;
        float e2z = e0x*e1y - e0y*e1x;

        float Ru[3][3] = { { e0x, e1x, e2x },
                           { e0y, e1y, e2y },
                           { e0z, e1z, e2z } };
        float tu[3] = { trans[0], trans[1], trans[2] };
        if (amask[row] == 0) {
            Ru[0][0]=1.f; Ru[0][1]=0.f; Ru[0][2]=0.f;
            Ru[1][0]=0.f; Ru[1][1]=1.f; Ru[1][2]=0.f;
            Ru[2][0]=0.f; Ru[2][1]=0.f; Ru[2][2]=1.f;
            tu[0]=tu[1]=tu[2]=0.f;
        }

        const float* af = affine + (size_t)row * 12;
        float R0[3][3] = { { af[0], af[1], af[2] },
                           { af[3], af[4], af[5] },
                           { af[6], af[7], af[8] } };
        float t0[3] = { af[9], af[10], af[11] };

        float R[3][3], t[3];
        #pragma unroll
        for (int i = 0; i < 3; ++i) {
            #pragma unroll
            for (int j = 0; j < 3; ++j)
                R[i][j] = R0[i][0]*Ru[0][j] + R0[i][1]*Ru[1][j] + R0[i][2]*Ru[2][j];
            t[i] = R0[i][0]*tu[0] + R0[i][1]*tu[1] + R0[i][2]*tu[2] + t0[i];
        }

        float* oa = out + (size_t)row * 12;
        #pragma unroll
        for (int i = 0; i < 3; ++i) {
            #pragma unroll
            for (int j = 0; j < 3; ++j) oa[i*3 + j] = R[i][j];
            oa[9 + i] = t[i];
        }

        const float BB[3][3] = { { -0.525f, 1.363f, 0.f },
                                 {  0.f,    0.f,   0.f },
                                 {  1.526f, 0.f,   0.f } };
        float* op = out + AFF_SZ + (size_t)row * 9;
        #pragma unroll
        for (int a = 0; a < 3; ++a)
            #pragma unroll
            for (int i = 0; i < 3; ++i)
                op[a*3 + i] = R[i][0]*BB[a][0] + R[i][1]*BB[a][1] + R[i][2]*BB[a][2] + t[i];
    }
}

// ===========================================================================
// LEGACY PATH — verbatim structure of the harness-verified 149 µs kernel.
// Used only when ws_size cannot hold the pre-converted operands.
// ===========================================================================

__global__ __launch_bounds__(256, 2)
void gemm1_legacy(const float* __restrict__ A, const float* __restrict__ Bm,
                  const float* __restrict__ b1, unsigned short* __restrict__ Hb)
{
    __shared__ __align__(16) unsigned short As[128][72];
    __shared__ __align__(16) unsigned short Bs[128][72];

    const int tid    = threadIdx.x;
    const int wave   = tid >> 6;
    const int lane   = tid & 63;
    const int wm     = (wave & 1) * 64;
    const int wn     = (wave >> 1) * 64;
    const int lane15 = lane & 15;
    const int quad   = lane >> 4;

    const int row0 = blockIdx.x * 128;
    const int col0 = blockIdx.y * 128;

    const int rbase = tid >> 4;
    const int c4    = (tid & 15) << 2;

    const float* Ab = A  + (size_t)(row0 + rbase) * DK + c4;
    const float* Bb = Bm + (size_t)(col0 + rbase) * DK + c4;

    floatx4 acc[4][4] = {};
    float4 pa[8], pb[8];

    #pragma unroll
    for (int i = 0; i < 8; ++i) {
        pa[i] = *(const float4*)(Ab + (size_t)(16 * i) * DK);
        pb[i] = *(const float4*)(Bb + (size_t)(16 * i) * DK);
    }

    for (int k0 = 0; k0 < DK; k0 += 64) {
        #pragma unroll
        for (int i = 0; i < 8; ++i) {
            unsigned int lo = pkbf(pa[i].x, pa[i].y);
            unsigned int hi = pkbf(pa[i].z, pa[i].w);
            *(uint2*)(&As[rbase + 16 * i][c4]) = make_uint2(lo, hi);
            lo = pkbf(pb[i].x, pb[i].y);
            hi = pkbf(pb[i].z, pb[i].w);
            *(uint2*)(&Bs[rbase + 16 * i][c4]) = make_uint2(lo, hi);
        }
        if (k0 + 64 < DK) {
            #pragma unroll
            for (int i = 0; i < 8; ++i) {
                pa[i] = *(const float4*)(Ab + (size_t)(16 * i) * DK + k0 + 64);
                pb[i] = *(const float4*)(Bb + (size_t)(16 * i) * DK + k0 + 64);
            }
        }
        __syncthreads();

        #pragma unroll
        for (int ks = 0; ks < 2; ++ks) {
            bf16x8 af[4], bfr[4];
            #pragma unroll
            for (int mt = 0; mt < 4; ++mt)
                af[mt] = *(const bf16x8*)(&As[wm + mt * 16 + lane15][ks * 32 + quad * 8]);
            #pragma unroll
            for (int nt = 0; nt < 4; ++nt)
                bfr[nt] = *(const bf16x8*)(&Bs[wn + nt * 16 + lane15][ks * 32 + quad * 8]);
            #pragma unroll
            for (int mt = 0; mt < 4; ++mt)
                #pragma unroll
                for (int nt = 0; nt < 4; ++nt)
                    acc[mt][nt] = __builtin_amdgcn_mfma_f32_16x16x32_bf16(
                        af[mt], bfr[nt], acc[mt][nt], 0, 0, 0);
        }
        __syncthreads();
    }

    #pragma unroll
    for (int mt = 0; mt < 4; ++mt)
        #pragma unroll
        for (int nt = 0; nt < 4; ++nt)
            #pragma unroll
            for (int r = 0; r < 4; ++r) {
                int row = row0 + wm + mt * 16 + quad * 4 + r;
                int col = col0 + wn + nt * 16 + lane15;
                float v = acc[mt][nt][r] + b1[col];
                v = 0.5f * v * (1.0f + erff(v * 0.70710678118654752f));
                Hb[(size_t)row * NOUT + col] = f2bf1(v);
            }
}

__global__ __launch_bounds__(256)
void head_legacy(const unsigned short* __restrict__ Hb, const float* __restrict__ ln_g,
                 const float* __restrict__ ln_b, const float* __restrict__ w2,
                 const float* __restrict__ b2, const float* __restrict__ affine,
                 const int* __restrict__ amask, float* __restrict__ out)
{
    __shared__ __align__(16) unsigned short hb[8][HSTRIDE];
    __shared__ float st[8][2];
    __shared__ float pred[2][16][17];
    __shared__ float pr[8][32];

    const int tid    = threadIdx.x;
    const int lane   = tid & 63;
    const int wave   = tid >> 6;
    const int lane15 = lane & 15;
    const int quad   = lane >> 4;
    const int row8   = blockIdx.x * 8;

    #pragma unroll
    for (int rr = 0; rr < 2; ++rr) {
        const int r = wave * 2 + rr;
        const unsigned short* src = Hb + (size_t)(row8 + r) * DK;
        float s = 0.f, ss = 0.f;
        #pragma unroll
        for (int j = 0; j < 3; ++j) {
            const int e8 = lane + 64 * j;
            uint4 u = *(const uint4*)(src + e8 * 8);
            *(uint4*)(&hb[r][e8 * 8]) = u;
            float f0 = bflo(u.x), f1 = bfhi(u.x), f2 = bflo(u.y), f3 = bfhi(u.y);
            float f4 = bflo(u.z), f5 = bfhi(u.z), f6 = bflo(u.w), f7 = bfhi(u.w);
            s  += ((f0 + f1) + (f2 + f3)) + ((f4 + f5) + (f6 + f7));
            ss += ((f0*f0 + f1*f1) + (f2*f2 + f3*f3)) + ((f4*f4 + f5*f5) + (f6*f6 + f7*f7));
        }
        #pragma unroll
        for (int off = 32; off > 0; off >>= 1) {
            s  += __shfl_down(s, off, 64);
            ss += __shfl_down(ss, off, 64);
        }
        if (lane == 0) {
            float mu  = s * (1.f / DK);
            float var = ss * (1.f / DK) - mu * mu;
            st[r][0] = mu;
            st[r][1] = 1.f / sqrtf(var + 1e-5f);
        }
    }
    __syncthreads();

    {
        const int r   = tid >> 5;
        const int c32 = tid & 31;
        const float mu = st[r][0], rstd = st[r][1];
        const float murstd = mu * rstd;
        #pragma unroll
        for (int jj = 0; jj < 6; ++jj) {
            const int e8 = c32 + 32 * jj;
            const int d  = e8 * 8;
            uint4 u = *(uint4*)(&hb[r][d]);
            float4 g0 = *(const float4*)(ln_g + d);
            float4 g1 = *(const float4*)(ln_g + d + 4);
            float4 b0 = *(const float4*)(ln_b + d);
            float4 b1v = *(const float4*)(ln_b + d + 4);
            float h0 = fmaf(bflo(u.x), rstd, -murstd), h1 = fmaf(bfhi(u.x), rstd, -murstd);
            float h2 = fmaf(bflo(u.y), rstd, -murstd), h3 = fmaf(bfhi(u.y), rstd, -murstd);
            float h4 = fmaf(bflo(u.z), rstd, -murstd), h5 = fmaf(bfhi(u.z), rstd, -murstd);
            float h6 = fmaf(bflo(u.w), rstd, -murstd), h7 = fmaf(bfhi(u.w), rstd, -murstd);
            h0 = fmaf(h0, g0.x, b0.x);  h1 = fmaf(h1, g0.y, b0.y);
            h2 = fmaf(h2, g0.z, b0.z);  h3 = fmaf(h3, g0.w, b0.w);
            h4 = fmaf(h4, g1.x, b1v.x); h5 = fmaf(h5, g1.y, b1v.y);
            h6 = fmaf(h6, g1.z, b1v.z); h7 = fmaf(h7, g1.w, b1v.w);
            u.x = pkbf(h0, h1); u.y = pkbf(h2, h3);
            u.z = pkbf(h4, h5); u.w = pkbf(h6, h7);
            *(uint4*)(&hb[r][d]) = u;
        }
    }
    __syncthreads();

    {
        const int ntile = wave & 1;
        const int khalf = wave >> 1;
        const int o     = ntile * 16 + lane15;
        const int osafe = (o < OUTC) ? o : 0;
        const float* wrow = w2 + (size_t)osafe * DK;
        const int mrow  = lane15 & 7;

        floatx4 acc = {0.f, 0.f, 0.f, 0.f};
        #pragma unroll 4
        for (int kk = 0; kk < 24; ++kk) {
            const int kb = khalf * 768 + kk * 32 + quad * 8;
            bf16x8 afr = *(const bf16x8*)(&hb[mrow][kb]);
            float4 wa = *(const float4*)(wrow + kb);
            float4 wb = *(const float4*)(wrow + kb + 4);
            union { unsigned int u[4]; bf16x8 v; } bu;
            bu.u[0] = pkbf(wa.x, wa.y);
            bu.u[1] = pkbf(wa.z, wa.w);
            bu.u[2] = pkbf(wb.x, wb.y);
            bu.u[3] = pkbf(wb.z, wb.w);
            acc = __builtin_amdgcn_mfma_f32_16x16x32_bf16(afr, bu.v, acc, 0, 0, 0);
        }

        if (khalf == 1) {
            #pragma unroll
            for (int r2 = 0; r2 < 4; ++r2)
                pred[ntile][quad * 4 + r2][lane15] = acc[r2];
        }
        __syncthreads();
        if (khalf == 0) {
            #pragma unroll
            for (int r2 = 0; r2 < 4; ++r2) {
                const int row = quad * 4 + r2;
                if (row < 8 && o < OUTC)
                    pr[row][o] = acc[r2] + pred[ntile][row][lane15] + b2[o];
            }
        }
    }
    __syncthreads();

    if (tid < 8) {
        const int row = row8 + tid;
        float p[OUTC];
        #pragma unroll
        for (int oo = 0; oo < OUTC; ++oo) p[oo] = pr[tid][oo];

        float trans[3] = { p[0] * 10.f, p[1] * 10.f, p[2] * 10.f };
        float xv[3] = { p[3], p[4], p[5] };
        float yv[3] = { p[6], p[7], p[8] };
        float xn = sqrtf(xv[0]*xv[0] + xv[1]*xv[1] + xv[2]*xv[2]) + 1e-5f;
        xv[0] /= xn; xv[1] /= xn; xv[2] /= xn;
        float yn = sqrtf(yv[0]*yv[0] + yv[1]*yv[1] + yv[2]*yv[2]) + 1e-5f;
        yv[0] /= yn; yv[1] /= yn; yv[2] /= yn;

        float a0 = -xv[0], a1 = -xv[1], a2 = -xv[2];
        float inv = 1.f / sqrtf(a0*a0 + a1*a1 + a2*a2 + 1e-12f);
        float e0x = a0 * inv, e0y = a1 * inv, e0z = a2 * inv;
        float c = e0x*yv[0] + e0y*yv[1] + e0z*yv[2];
        float e1x = yv[0] - e0x * c, e1y = yv[1] - e0y * c, e1z = yv[2] - e0z * c;
        inv = 1.f / sqrtf(e1x*e1x + e1y*e1y + e1z*e1z + 1e-12f);
        e1x *= inv; e1y *= inv; e1z *= inv;
        float e2x = e0y*e1z - e0z*e1y;
        float e2y = e0z*e1x - e0x*e1z;
        float e2z = e0x*e1y - e0y*e1x;

        float Ru[3][3] = { { e0x, e1x, e2x },
                           { e0y, e1y, e2y },
                           { e0z, e1z, e2z } };
        float tu[3] = { trans[0], trans[1], trans[2] };
        if (amask[row] == 0) {
            Ru[0][0]=1.f; Ru[0][1]=0.f; Ru[0][2]=0.f;
            Ru[1][0]=0.f; Ru[1][1]=1.f; Ru[1][2]=0.f;
            Ru[2][0]=0.f; Ru[2][1]=0.f; Ru[2][2]=1.f;
            tu[0]=tu[1]=tu[2]=0.f;
        }

        const float* af = affine + (size_t)row * 12;
        float R0[3][3] = { { af[0], af[1], af[2] },
                           { af[3], af[4], af[5] },
                           { af[6], af[7], af[8] } };
        float t0[3] = { af[9], af[10], af[11] };

        float R[3][3], t[3];
        #pragma unroll
        for (int i = 0; i < 3; ++i) {
            #pragma unroll
            for (int j = 0; j < 3; ++j)
                R[i][j] = R0[i][0]*Ru[0][j] + R0[i][1]*Ru[1][j] + R0[i][2]*Ru[2][j];
            t[i] = R0[i][0]*tu[0] + R0[i][1]*tu[1] + R0[i][2]*tu[2] + t0[i];
        }

        float* oa = out + (size_t)row * 12;
        #pragma unroll
        for (int i = 0; i < 3; ++i) {
            #pragma unroll
            for (int j = 0; j < 3; ++j) oa[i*3 + j] = R[i][j];
            oa[9 + i] = t[i];
        }

        const float BB[3][3] = { { -0.525f, 1.363f, 0.f },
                                 {  0.f,    0.f,   0.f },
                                 {  1.526f, 0.f,   0.f } };
        float* op = out + AFF_SZ + (size_t)row * 9;
        #pragma unroll
        for (int a = 0; a < 3; ++a)
            #pragma unroll
            for (int i = 0; i < 3; ++i)
                op[a*3 + i] = R[i][0]*BB[a][0] + R[i][1]*BB[a][1] + R[i][2]*BB[a][2] + t[i];
    }
}

extern "C" void kernel_launch(void* const* d_in, const int* in_sizes, int n_in,
                              void* d_out, int out_size, void* d_ws, size_t ws_size,
                              hipStream_t stream) {
    const float* x      = (const float*)d_in[0];
    const float* affine = (const float*)d_in[1];
    const int*   amask  = (const int*)  d_in[2];
    const float* w1     = (const float*)d_in[3];
    const float* b1     = (const float*)d_in[4];
    const float* ln_g   = (const float*)d_in[5];
    const float* ln_b   = (const float*)d_in[6];
    const float* w2     = (const float*)d_in[7];
    const float* b2     = (const float*)d_in[8];
    float* out = (float*)d_out;

    const size_t HB_ELEMS  = (size_t)MROWS * DK;     // 6.29 M
    const size_t W1_ELEMS  = (size_t)DK * DK;        // 2.36 M
    const size_t W2_ELEMS  = (size_t)OUTC * DK;      // 35 K
    const size_t FAST_BYTES = (2 * HB_ELEMS + W1_ELEMS + W2_ELEMS) * sizeof(unsigned short);

    unsigned short* Hb = (unsigned short*)d_ws;

    if (ws_size >= FAST_BYTES) {
        // workspace layout (bf16): Hb | xb | w1b | w2b  (~30 MB)
        unsigned short* xb  = Hb  + HB_ELEMS;
        unsigned short* w1b = xb  + HB_ELEMS;
        unsigned short* w2b = w1b + W1_ELEMS;

        convert_kernel<<<2048, 256, 0, stream>>>(x, w1, w2, xb, w1b, w2b);
        dim3 g1f(MROWS / 128, NOUT / 96);   // 32 x 16 = 512 blocks = 2/CU exact
        gemm1_fast<<<g1f, 256, 0, stream>>>(xb, w1b, b1, Hb);
        head_fast<<<MROWS / 8, 256, 0, stream>>>(Hb, ln_g, ln_b, w2b, b2, affine, amask, out);
    } else {
        // known-good 149 µs path (workspace = Hb only, 12.6 MB)
        dim3 g1(MROWS / 128, NOUT / 128);   // 32 x 12 = 384 blocks
        gemm1_legacy<<<g1, 256, 0, stream>>>(x, w1, b1, Hb);
        head_legacy<<<MROWS / 8, 256, 0, stream>>>(Hb, ln_g, ln_b, w2, b2, affine, amask, out);
    }
}

// Round 10
// 130.783 us; speedup vs baseline: 1.0451x; 1.0395x over previous
//
#include <hip/hip_runtime.h>
#include <hip/hip_bf16.h>
#include <math.h>

typedef __bf16 bf16x8 __attribute__((ext_vector_type(8)));
typedef float floatx4 __attribute__((ext_vector_type(4)));

#define DK    1536   // inner dim D
#define MROWS 4096   // B*L
#define NOUT  1536   // first GEMM output dim
#define OUTC  23     // second GEMM output dim
#define AFF_SZ (MROWS * 12)
#define HSTRIDE 1544 // bf16 row stride in head LDS (+8 pad)

// round-to-nearest (ties up) fp32 -> bf16 bits
__device__ __forceinline__ unsigned int pkbf(float lo, float hi) {
    unsigned int a = __float_as_uint(lo) + 0x8000u;
    unsigned int b = __float_as_uint(hi) + 0x8000u;
    return (b & 0xffff0000u) | (a >> 16);
}
__device__ __forceinline__ unsigned short f2bf1(float v) {
    return (unsigned short)((__float_as_uint(v) + 0x8000u) >> 16);
}
__device__ __forceinline__ float bflo(unsigned int u) {
    return __uint_as_float(u << 16);
}
__device__ __forceinline__ float bfhi(unsigned int u) {
    return __uint_as_float(u & 0xffff0000u);
}

// async global->LDS, 16B per lane. LDS dest is wave-uniform base;
// HW writes base + lane*16. Global src is per-lane.
__device__ __forceinline__ void async16(const unsigned short* g, unsigned short* l) {
    __builtin_amdgcn_global_load_lds(
        (const __attribute__((address_space(1))) unsigned int*)(g),
        (__attribute__((address_space(3))) unsigned int*)(l), 16, 0, 0);
}

// ===========================================================================
// FAST PATH. Ledger: R0 pre-convert+gload_lds −10.3 · R4 regrid −2.9 ·
// R6 dbuf +5.4 (REVERTED) · R8 head-16row +1.3 (REVERTED).
// R9 rocprof (first direct gemm1 counters): gemm1 = 61.8 µs, MfmaUtil 12%,
// VALUBusy 15%, HBM 7.7%, Occupancy 21% (grid-limited 2 blocks/CU) →
// LATENCY-BOUND, barrier vmcnt(0) drain exposed 24x with ~2 waves/SIMD TLP.
// R10 (this): 64x96 tile -> 1024 blocks = 4/CU = ~50% occupancy (TLP fix).
// ===========================================================================

// ---------------------------------------------------------------------------
// Kernel 0: one-shot fp32 -> bf16 conversion of x, w1, w2 (memory-bound).
// ---------------------------------------------------------------------------
__global__ __launch_bounds__(256)
void convert_kernel(const float* __restrict__ x, const float* __restrict__ w1,
                    const float* __restrict__ w2, unsigned short* __restrict__ xb,
                    unsigned short* __restrict__ w1b, unsigned short* __restrict__ w2b)
{
    const int NX8  = (MROWS * DK) / 8;   // 786432
    const int NW18 = (DK * DK) / 8;      // 294912
    const int NW28 = (OUTC * DK) / 8;    // 4416
    const int TOT  = NX8 + NW18 + NW28;
    for (int i = blockIdx.x * blockDim.x + threadIdx.x; i < TOT;
         i += gridDim.x * blockDim.x) {
        const float* src; unsigned short* dst; int j;
        if (i < NX8)             { src = x;  dst = xb;  j = i; }
        else if (i < NX8 + NW18) { src = w1; dst = w1b; j = i - NX8; }
        else                     { src = w2; dst = w2b; j = i - NX8 - NW18; }
        float4 a = *(const float4*)(src + (size_t)j * 8);
        float4 b = *(const float4*)(src + (size_t)j * 8 + 4);
        uint4 u;
        u.x = pkbf(a.x, a.y); u.y = pkbf(a.z, a.w);
        u.z = pkbf(b.x, b.y); u.w = pkbf(b.z, b.w);
        *(uint4*)(dst + (size_t)j * 8) = u;
    }
}

// ---------------------------------------------------------------------------
// Kernel 1 (fast): Hb = bf16( gelu(xb @ w1b^T + b1) )  [M=4096,N=1536,K=1536]
// 64x96 tile, grid 64x16 = 1024 blocks = 4 blocks/CU (16 waves/CU, ~50% occ).
// BK=64, 4 waves (2M x 2N), per-wave 32x48 (acc[2][3]). global_load_lds
// width 16, single LDS buffer (20.5 KB), 2 barriers per K-step.
// Rule-#21 both-sides XOR chunk swizzle (invariants preserved: wm=32-mult,
// wn=48-mult, mt/nt*16 — all 8-multiples → fragment R&7 == lane15&7;
// staging row_local&7 == lane>>3 since wave*8, i*32 are 8-multiples).
// ---------------------------------------------------------------------------
__global__ __launch_bounds__(256, 4)
void gemm1_fast(const unsigned short* __restrict__ A, const unsigned short* __restrict__ Bm,
                const float* __restrict__ b1, unsigned short* __restrict__ Hb)
{
    __shared__ __align__(16) unsigned short As[64 * 64];
    __shared__ __align__(16) unsigned short Bs[96 * 64];

    const int tid    = threadIdx.x;
    const int wave   = tid >> 6;
    const int lane   = tid & 63;
    const int lane15 = lane & 15;
    const int quad   = lane >> 4;
    const int wm     = (wave & 1) * 32;   // M offset of wave tile (32 = 4*8)
    const int wn     = (wave >> 1) * 48;  // N offset of wave tile (48 = 6*8)
    const int sw     = lane15 & 7;        // == R&7 for all fragment rows this lane reads

    const int row0 = blockIdx.x * 64;
    const int col0 = blockIdx.y * 96;

    // staging: one async16 covers 8 rows x 64 cols (64 lanes x 16B).
    // lane l -> row + (l>>3), K-chunk (l&7) ^ (l>>3)  [inverse swizzle].
    const int lr = lane >> 3;
    const int lc = (lane & 7) ^ lr;

    const unsigned short* ga = A  + (size_t)(row0 + wave * 8 + lr) * DK + lc * 8;
    const unsigned short* gb = Bm + (size_t)(col0 + wave * 8 + lr) * DK + lc * 8;

    unsigned short* lasA = &As[(wave * 8) * 64];   // wave-uniform
    unsigned short* lasB = &Bs[(wave * 8) * 64];

    floatx4 acc[2][3] = {};

    for (int k0 = 0; k0 < DK; k0 += 64) {
        #pragma unroll
        for (int i = 0; i < 2; ++i)        // A: 4 waves x 2 calls x 8 rows = 64
            async16(ga + (size_t)(i * 32) * DK + k0, lasA + i * 32 * 64);
        #pragma unroll
        for (int i = 0; i < 3; ++i)        // B: 4 waves x 3 calls x 8 rows = 96
            async16(gb + (size_t)(i * 32) * DK + k0, lasB + i * 32 * 64);
        __syncthreads();   // compiler emits vmcnt(0) drain before s_barrier

        #pragma unroll
        for (int ks = 0; ks < 2; ++ks) {
            bf16x8 af[2], bfr[3];
            #pragma unroll
            for (int mt = 0; mt < 2; ++mt) {
                const int R = wm + mt * 16 + lane15;
                const int q = (ks * 4 + quad) ^ sw;
                af[mt] = *(const bf16x8*)(&As[R * 64 + q * 8]);
            }
            #pragma unroll
            for (int nt = 0; nt < 3; ++nt) {
                const int R = wn + nt * 16 + lane15;
                const int q = (ks * 4 + quad) ^ sw;
                bfr[nt] = *(const bf16x8*)(&Bs[R * 64 + q * 8]);
            }
            #pragma unroll
            for (int mt = 0; mt < 2; ++mt)
                #pragma unroll
                for (int nt = 0; nt < 3; ++nt)
                    acc[mt][nt] = __builtin_amdgcn_mfma_f32_16x16x32_bf16(
                        af[mt], bfr[nt], acc[mt][nt], 0, 0, 0);
        }
        __syncthreads();
    }

    #pragma unroll
    for (int mt = 0; mt < 2; ++mt)
        #pragma unroll
        for (int nt = 0; nt < 3; ++nt)
            #pragma unroll
            for (int r = 0; r < 4; ++r) {
                int row = row0 + wm + mt * 16 + quad * 4 + r;
                int col = col0 + wn + nt * 16 + lane15;
                float v = acc[mt][nt][r] + b1[col];
                v = 0.5f * v * (1.0f + erff(v * 0.70710678118654752f));
                Hb[(size_t)row * NOUT + col] = f2bf1(v);
            }
}

// ---------------------------------------------------------------------------
// Kernel 2 (fast): head, 8 rows/block (512 blocks, 2/CU) — R7 best-measured.
// ---------------------------------------------------------------------------
__global__ __launch_bounds__(256)
void head_fast(const unsigned short* __restrict__ Hb, const float* __restrict__ ln_g,
               const float* __restrict__ ln_b, const unsigned short* __restrict__ w2b,
               const float* __restrict__ b2, const float* __restrict__ affine,
               const int* __restrict__ amask, float* __restrict__ out)
{
    __shared__ __align__(16) unsigned short hb[8][HSTRIDE];
    __shared__ float st[8][2];
    __shared__ float pred[2][16][17];
    __shared__ float pr[8][32];

    const int tid    = threadIdx.x;
    const int lane   = tid & 63;
    const int wave   = tid >> 6;
    const int lane15 = lane & 15;
    const int quad   = lane >> 4;
    const int row8   = blockIdx.x * 8;

    #pragma unroll
    for (int rr = 0; rr < 2; ++rr) {
        const int r = wave * 2 + rr;
        const unsigned short* src = Hb + (size_t)(row8 + r) * DK;
        float s = 0.f, ss = 0.f;
        #pragma unroll
        for (int j = 0; j < 3; ++j) {
            const int e8 = lane + 64 * j;
            uint4 u = *(const uint4*)(src + e8 * 8);
            *(uint4*)(&hb[r][e8 * 8]) = u;
            float f0 = bflo(u.x), f1 = bfhi(u.x), f2 = bflo(u.y), f3 = bfhi(u.y);
            float f4 = bflo(u.z), f5 = bfhi(u.z), f6 = bflo(u.w), f7 = bfhi(u.w);
            s  += ((f0 + f1) + (f2 + f3)) + ((f4 + f5) + (f6 + f7));
            ss += ((f0*f0 + f1*f1) + (f2*f2 + f3*f3)) + ((f4*f4 + f5*f5) + (f6*f6 + f7*f7));
        }
        #pragma unroll
        for (int off = 32; off > 0; off >>= 1) {
            s  += __shfl_down(s, off, 64);
            ss += __shfl_down(ss, off, 64);
        }
        if (lane == 0) {
            float mu  = s * (1.f / DK);
            float var = ss * (1.f / DK) - mu * mu;
            st[r][0] = mu;
            st[r][1] = 1.f / sqrtf(var + 1e-5f);
        }
    }
    __syncthreads();

    {
        const int r   = tid >> 5;
        const int c32 = tid & 31;
        const float mu = st[r][0], rstd = st[r][1];
        const float murstd = mu * rstd;
        #pragma unroll
        for (int jj = 0; jj < 6; ++jj) {
            const int e8 = c32 + 32 * jj;
            const int d  = e8 * 8;
            uint4 u = *(uint4*)(&hb[r][d]);
            float4 g0 = *(const float4*)(ln_g + d);
            float4 g1 = *(const float4*)(ln_g + d + 4);
            float4 b0 = *(const float4*)(ln_b + d);
            float4 b1v = *(const float4*)(ln_b + d + 4);
            float h0 = fmaf(bflo(u.x), rstd, -murstd), h1 = fmaf(bfhi(u.x), rstd, -murstd);
            float h2 = fmaf(bflo(u.y), rstd, -murstd), h3 = fmaf(bfhi(u.y), rstd, -murstd);
            float h4 = fmaf(bflo(u.z), rstd, -murstd), h5 = fmaf(bfhi(u.z), rstd, -murstd);
            float h6 = fmaf(bflo(u.w), rstd, -murstd), h7 = fmaf(bfhi(u.w), rstd, -murstd);
            h0 = fmaf(h0, g0.x, b0.x);  h1 = fmaf(h1, g0.y, b0.y);
            h2 = fmaf(h2, g0.z, b0.z);  h3 = fmaf(h3, g0.w, b0.w);
            h4 = fmaf(h4, g1.x, b1v.x); h5 = fmaf(h5, g1.y, b1v.y);
            h6 = fmaf(h6, g1.z, b1v.z); h7 = fmaf(h7, g1.w, b1v.w);
            u.x = pkbf(h0, h1); u.y = pkbf(h2, h3);
            u.z = pkbf(h4, h5); u.w = pkbf(h6, h7);
            *(uint4*)(&hb[r][d]) = u;
        }
    }
    __syncthreads();

    {
        const int ntile = wave & 1;
        const int khalf = wave >> 1;
        const int o     = ntile * 16 + lane15;
        const int osafe = (o < OUTC) ? o : 0;
        const unsigned short* wrow = w2b + (size_t)osafe * DK;
        const int mrow  = lane15 & 7;

        floatx4 acc = {0.f, 0.f, 0.f, 0.f};
        #pragma unroll 4
        for (int kk = 0; kk < 24; ++kk) {
            const int kb = khalf * 768 + kk * 32 + quad * 8;
            bf16x8 afr = *(const bf16x8*)(&hb[mrow][kb]);
            bf16x8 bfr = *(const bf16x8*)(wrow + kb);
            acc = __builtin_amdgcn_mfma_f32_16x16x32_bf16(afr, bfr, acc, 0, 0, 0);
        }

        if (khalf == 1) {
            #pragma unroll
            for (int r2 = 0; r2 < 4; ++r2)
                pred[ntile][quad * 4 + r2][lane15] = acc[r2];
        }
        __syncthreads();
        if (khalf == 0) {
            #pragma unroll
            for (int r2 = 0; r2 < 4; ++r2) {
                const int row = quad * 4 + r2;
                if (row < 8 && o < OUTC)
                    pr[row][o] = acc[r2] + pred[ntile][row][lane15] + b2[o];
            }
        }
    }
    __syncthreads();

    if (tid < 8) {
        const int row = row8 + tid;
        float p[OUTC];
        #pragma unroll
        for (int oo = 0; oo < OUTC; ++oo) p[oo] = pr[tid][oo];

        float trans[3] = { p[0] * 10.f, p[1] * 10.f, p[2] * 10.f };
        float xv[3] = { p[3], p[4], p[5] };
        float yv[3] = { p[6], p[7], p[8] };
        float xn = sqrtf(xv[0]*xv[0] + xv[1]*xv[1] + xv[2]*xv[2]) + 1e-5f;
        xv[0] /= xn; xv[1] /= xn; xv[2] /= xn;
        float yn = sqrtf(yv[0]*yv[0] + yv[1]*yv[1] + yv[2]*yv[2]) + 1e-5f;
        yv[0] /= yn; yv[1] /= yn; yv[2] /= yn;

        float a0 = -xv[0], a1 = -xv[1], a2 = -xv[2];
        float inv = 1.f / sqrtf(a0*a0 + a1*a1 + a2*a2 + 1e-12f);
        float e0x = a0 * inv, e0y = a1 * inv, e0z = a2 * inv;
        float c = e0x*yv[0] + e0y*yv[1] + e0z*yv[2];
        float e1x = yv[0] - e0x * c, e1y = yv[1] - e0y * c, e1z = yv[2] - e0z * c;
        inv = 1.f / sqrtf(e1x*e1x + e1y*e1y + e1z*e1z + 1e-12f);
        e1x *= inv; e1y *= inv; e1z *= inv;
        float e2x = e0y*e1z - e0z*e1y;
        float e2y = e0z*e1x - e0x*e1z;
        float e2z = e0x*e1y - e0y*e1x;

        float Ru[3][3] = { { e0x, e1x, e2x },
                           { e0y, e1y, e2y },
                           { e0z, e1z, e2z } };
        float tu[3] = { trans[0], trans[1], trans[2] };
        if (amask[row] == 0) {
            Ru[0][0]=1.f; Ru[0][1]=0.f; Ru[0][2]=0.f;
            Ru[1][0]=0.f; Ru[1][1]=1.f; Ru[1][2]=0.f;
            Ru[2][0]=0.f; Ru[2][1]=0.f; Ru[2][2]=1.f;
            tu[0]=tu[1]=tu[2]=0.f;
        }

        const float* af = affine + (size_t)row * 12;
        float R0[3][3] = { { af[0], af[1], af[2] },
                           { af[3], af[4], af[5] },
                           { af[6], af[7], af[8] } };
        float t0[3] = { af[9], af[10], af[11] };

        float R[3][3], t[3];
        #pragma unroll
        for (int i = 0; i < 3; ++i) {
            #pragma unroll
            for (int j = 0; j < 3; ++j)
                R[i][j] = R0[i][0]*Ru[0][j] + R0[i][1]*Ru[1][j] + R0[i][2]*Ru[2][j];
            t[i] = R0[i][0]*tu[0] + R0[i][1]*tu[1] + R0[i][2]*tu[2] + t0[i];
        }

        float* oa = out + (size_t)row * 12;
        #pragma unroll
        for (int i = 0; i < 3; ++i) {
            #pragma unroll
            for (int j = 0; j < 3; ++j) oa[i*3 + j] = R[i][j];
            oa[9 + i] = t[i];
        }

        const float BB[3][3] = { { -0.525f, 1.363f, 0.f },
                                 {  0.f,    0.f,   0.f },
                                 {  1.526f, 0.f,   0.f } };
        float* op = out + AFF_SZ + (size_t)row * 9;
        #pragma unroll
        for (int a = 0; a < 3; ++a)
            #pragma unroll
            for (int i = 0; i < 3; ++i)
                op[a*3 + i] = R[i][0]*BB[a][0] + R[i][1]*BB[a][1] + R[i][2]*BB[a][2] + t[i];
    }
}

// ===========================================================================
// LEGACY PATH — verbatim structure of the harness-verified 149 µs kernel.
// Used only when ws_size cannot hold the pre-converted operands.
// ===========================================================================

__global__ __launch_bounds__(256, 2)
void gemm1_legacy(const float* __restrict__ A, const float* __restrict__ Bm,
                  const float* __restrict__ b1, unsigned short* __restrict__ Hb)
{
    __shared__ __align__(16) unsigned short As[128][72];
    __shared__ __align__(16) unsigned short Bs[128][72];

    const int tid    = threadIdx.x;
    const int wave   = tid >> 6;
    const int lane   = tid & 63;
    const int wm     = (wave & 1) * 64;
    const int wn     = (wave >> 1) * 64;
    const int lane15 = lane & 15;
    const int quad   = lane >> 4;

    const int row0 = blockIdx.x * 128;
    const int col0 = blockIdx.y * 128;

    const int rbase = tid >> 4;
    const int c4    = (tid & 15) << 2;

    const float* Ab = A  + (size_t)(row0 + rbase) * DK + c4;
    const float* Bb = Bm + (size_t)(col0 + rbase) * DK + c4;

    floatx4 acc[4][4] = {};
    float4 pa[8], pb[8];

    #pragma unroll
    for (int i = 0; i < 8; ++i) {
        pa[i] = *(const float4*)(Ab + (size_t)(16 * i) * DK);
        pb[i] = *(const float4*)(Bb + (size_t)(16 * i) * DK);
    }

    for (int k0 = 0; k0 < DK; k0 += 64) {
        #pragma unroll
        for (int i = 0; i < 8; ++i) {
            unsigned int lo = pkbf(pa[i].x, pa[i].y);
            unsigned int hi = pkbf(pa[i].z, pa[i].w);
            *(uint2*)(&As[rbase + 16 * i][c4]) = make_uint2(lo, hi);
            lo = pkbf(pb[i].x, pb[i].y);
            hi = pkbf(pb[i].z, pb[i].w);
            *(uint2*)(&Bs[rbase + 16 * i][c4]) = make_uint2(lo, hi);
        }
        if (k0 + 64 < DK) {
            #pragma unroll
            for (int i = 0; i < 8; ++i) {
                pa[i] = *(const float4*)(Ab + (size_t)(16 * i) * DK + k0 + 64);
                pb[i] = *(const float4*)(Bb + (size_t)(16 * i) * DK + k0 + 64);
            }
        }
        __syncthreads();

        #pragma unroll
        for (int ks = 0; ks < 2; ++ks) {
            bf16x8 af[4], bfr[4];
            #pragma unroll
            for (int mt = 0; mt < 4; ++mt)
                af[mt] = *(const bf16x8*)(&As[wm + mt * 16 + lane15][ks * 32 + quad * 8]);
            #pragma unroll
            for (int nt = 0; nt < 4; ++nt)
                bfr[nt] = *(const bf16x8*)(&Bs[wn + nt * 16 + lane15][ks * 32 + quad * 8]);
            #pragma unroll
            for (int mt = 0; mt < 4; ++mt)
                #pragma unroll
                for (int nt = 0; nt < 4; ++nt)
                    acc[mt][nt] = __builtin_amdgcn_mfma_f32_16x16x32_bf16(
                        af[mt], bfr[nt], acc[mt][nt], 0, 0, 0);
        }
        __syncthreads();
    }

    #pragma unroll
    for (int mt = 0; mt < 4; ++mt)
        #pragma unroll
        for (int nt = 0; nt < 4; ++nt)
            #pragma unroll
            for (int r = 0; r < 4; ++r) {
                int row = row0 + wm + mt * 16 + quad * 4 + r;
                int col = col0 + wn + nt * 16 + lane15;
                float v = acc[mt][nt][r] + b1[col];
                v = 0.5f * v * (1.0f + erff(v * 0.70710678118654752f));
                Hb[(size_t)row * NOUT + col] = f2bf1(v);
            }
}

__global__ __launch_bounds__(256)
void head_legacy(const unsigned short* __restrict__ Hb, const float* __restrict__ ln_g,
                 const float* __restrict__ ln_b, const float* __restrict__ w2,
                 const float* __restrict__ b2, const float* __restrict__ affine,
                 const int* __restrict__ amask, float* __restrict__ out)
{
    __shared__ __align__(16) unsigned short hb[8][HSTRIDE];
    __shared__ float st[8][2];
    __shared__ float pred[2][16][17];
    __shared__ float pr[8][32];

    const int tid    = threadIdx.x;
    const int lane   = tid & 63;
    const int wave   = tid >> 6;
    const int lane15 = lane & 15;
    const int quad   = lane >> 4;
    const int row8   = blockIdx.x * 8;

    #pragma unroll
    for (int rr = 0; rr < 2; ++rr) {
        const int r = wave * 2 + rr;
        const unsigned short* src = Hb + (size_t)(row8 + r) * DK;
        float s = 0.f, ss = 0.f;
        #pragma unroll
        for (int j = 0; j < 3; ++j) {
            const int e8 = lane + 64 * j;
            uint4 u = *(const uint4*)(src + e8 * 8);
            *(uint4*)(&hb[r][e8 * 8]) = u;
            float f0 = bflo(u.x), f1 = bfhi(u.x), f2 = bflo(u.y), f3 = bfhi(u.y);
            float f4 = bflo(u.z), f5 = bfhi(u.z), f6 = bflo(u.w), f7 = bfhi(u.w);
            s  += ((f0 + f1) + (f2 + f3)) + ((f4 + f5) + (f6 + f7));
            ss += ((f0*f0 + f1*f1) + (f2*f2 + f3*f3)) + ((f4*f4 + f5*f5) + (f6*f6 + f7*f7));
        }
        #pragma unroll
        for (int off = 32; off > 0; off >>= 1) {
            s  += __shfl_down(s, off, 64);
            ss += __shfl_down(ss, off, 64);
        }
        if (lane == 0) {
            float mu  = s * (1.f / DK);
            float var = ss * (1.f / DK) - mu * mu;
            st[r][0] = mu;
            st[r][1] = 1.f / sqrtf(var + 1e-5f);
        }
    }
    __syncthreads();

    {
        const int r   = tid >> 5;
        const int c32 = tid & 31;
        const float mu = st[r][0], rstd = st[r][1];
        const float murstd = mu * rstd;
        #pragma unroll
        for (int jj = 0; jj < 6; ++jj) {
            const int e8 = c32 + 32 * jj;
            const int d  = e8 * 8;
            uint4 u = *(uint4*)(&hb[r][d]);
            float4 g0 = *(const float4*)(ln_g + d);
            float4 g1 = *(const float4*)(ln_g + d + 4);
            float4 b0 = *(const float4*)(ln_b + d);
            float4 b1v = *(const float4*)(ln_b + d + 4);
            float h0 = fmaf(bflo(u.x), rstd, -murstd), h1 = fmaf(bfhi(u.x), rstd, -murstd);
            float h2 = fmaf(bflo(u.y), rstd, -murstd), h3 = fmaf(bfhi(u.y), rstd, -murstd);
            float h4 = fmaf(bflo(u.z), rstd, -murstd), h5 = fmaf(bfhi(u.z), rstd, -murstd);
            float h6 = fmaf(bflo(u.w), rstd, -murstd), h7 = fmaf(bfhi(u.w), rstd, -murstd);
            h0 = fmaf(h0, g0.x, b0.x);  h1 = fmaf(h1, g0.y, b0.y);
            h2 = fmaf(h2, g0.z, b0.z);  h3 = fmaf(h3, g0.w, b0.w);
            h4 = fmaf(h4, g1.x, b1v.x); h5 = fmaf(h5, g1.y, b1v.y);
            h6 = fmaf(h6, g1.z, b1v.z); h7 = fmaf(h7, g1.w, b1v.w);
            u.x = pkbf(h0, h1); u.y = pkbf(h2, h3);
            u.z = pkbf(h4, h5); u.w = pkbf(h6, h7);
            *(uint4*)(&hb[r][d]) = u;
        }
    }
    __syncthreads();

    {
        const int ntile = wave & 1;
        const int khalf = wave >> 1;
        const int o     = ntile * 16 + lane15;
        const int osafe = (o < OUTC) ? o : 0;
        const float* wrow = w2 + (size_t)osafe * DK;
        const int mrow  = lane15 & 7;

        floatx4 acc = {0.f, 0.f, 0.f, 0.f};
        #pragma unroll 4
        for (int kk = 0; kk < 24; ++kk) {
            const int kb = khalf * 768 + kk * 32 + quad * 8;
            bf16x8 afr = *(const bf16x8*)(&hb[mrow][kb]);
            float4 wa = *(const float4*)(wrow + kb);
            float4 wb = *(const float4*)(wrow + kb + 4);
            union { unsigned int u[4]; bf16x8 v; } bu;
            bu.u[0] = pkbf(wa.x, wa.y);
            bu.u[1] = pkbf(wa.z, wa.w);
            bu.u[2] = pkbf(wb.x, wb.y);
            bu.u[3] = pkbf(wb.z, wb.w);
            acc = __builtin_amdgcn_mfma_f32_16x16x32_bf16(afr, bu.v, acc, 0, 0, 0);
        }

        if (khalf == 1) {
            #pragma unroll
            for (int r2 = 0; r2 < 4; ++r2)
                pred[ntile][quad * 4 + r2][lane15] = acc[r2];
        }
        __syncthreads();
        if (khalf == 0) {
            #pragma unroll
            for (int r2 = 0; r2 < 4; ++r2) {
                const int row = quad * 4 + r2;
                if (row < 8 && o < OUTC)
                    pr[row][o] = acc[r2] + pred[ntile][row][lane15] + b2[o];
            }
        }
    }
    __syncthreads();

    if (tid < 8) {
        const int row = row8 + tid;
        float p[OUTC];
        #pragma unroll
        for (int oo = 0; oo < OUTC; ++oo) p[oo] = pr[tid][oo];

        float trans[3] = { p[0] * 10.f, p[1] * 10.f, p[2] * 10.f };
        float xv[3] = { p[3], p[4], p[5] };
        float yv[3] = { p[6], p[7], p[8] };
        float xn = sqrtf(xv[0]*xv[0] + xv[1]*xv[1] + xv[2]*xv[2]) + 1e-5f;
        xv[0] /= xn; xv[1] /= xn; xv[2] /= xn;
        float yn = sqrtf(yv[0]*yv[0] + yv[1]*yv[1] + yv[2]*yv[2]) + 1e-5f;
        yv[0] /= yn; yv[1] /= yn; yv[2] /= yn;

        float a0 = -xv[0], a1 = -xv[1], a2 = -xv[2];
        float inv = 1.f / sqrtf(a0*a0 + a1*a1 + a2*a2 + 1e-12f);
        float e0x = a0 * inv, e0y = a1 * inv, e0z = a2 * inv;
        float c = e0x*yv[0] + e0y*yv[1] + e0z*yv[2];
        float e1x = yv[0] - e0x * c, e1y = yv[1] - e0y * c, e1z = yv[2] - e0z * c;
        inv = 1.f / sqrtf(e1x*e1x + e1y*e1y + e1z*e1z + 1e-12f);
        e1x *= inv; e1y *= inv; e1z *= inv;
        float e2x = e0y*e1z - e0z*e1y;
        float e2y = e0z*e1x - e0x*e1z;
        float e2z = e0x*e1y - e0y*e1x;

        float Ru[3][3] = { { e0x, e1x, e2x },
                           { e0y, e1y, e2y },
                           { e0z, e1z, e2z } };
        float tu[3] = { trans[0], trans[1], trans[2] };
        if (amask[row] == 0) {
            Ru[0][0]=1.f; Ru[0][1]=0.f; Ru[0][2]=0.f;
            Ru[1][0]=0.f; Ru[1][1]=1.f; Ru[1][2]=0.f;
            Ru[2][0]=0.f; Ru[2][1]=0.f; Ru[2][2]=1.f;
            tu[0]=tu[1]=tu[2]=0.f;
        }

        const float* af = affine + (size_t)row * 12;
        float R0[3][3] = { { af[0], af[1], af[2] },
                           { af[3], af[4], af[5] },
                           { af[6], af[7], af[8] } };
        float t0[3] = { af[9], af[10], af[11] };

        float R[3][3], t[3];
        #pragma unroll
        for (int i = 0; i < 3; ++i) {
            #pragma unroll
            for (int j = 0; j < 3; ++j)
                R[i][j] = R0[i][0]*Ru[0][j] + R0[i][1]*Ru[1][j] + R0[i][2]*Ru[2][j];
            t[i] = R0[i][0]*tu[0] + R0[i][1]*tu[1] + R0[i][2]*tu[2] + t0[i];
        }

        float* oa = out + (size_t)row * 12;
        #pragma unroll
        for (int i = 0; i < 3; ++i) {
            #pragma unroll
            for (int j = 0; j < 3; ++j) oa[i*3 + j] = R[i][j];
            oa[9 + i] = t[i];
        }

        const float BB[3][3] = { { -0.525f, 1.363f, 0.f },
                                 {  0.f,    0.f,   0.f },
                                 {  1.526f, 0.f,   0.f } };
        float* op = out + AFF_SZ + (size_t)row * 9;
        #pragma unroll
        for (int a = 0; a < 3; ++a)
            #pragma unroll
            for (int i = 0; i < 3; ++i)
                op[a*3 + i] = R[i][0]*BB[a][0] + R[i][1]*BB[a][1] + R[i][2]*BB[a][2] + t[i];
    }
}

extern "C" void kernel_launch(void* const* d_in, const int* in_sizes, int n_in,
                              void* d_out, int out_size, void* d_ws, size_t ws_size,
                              hipStream_t stream) {
    const float* x      = (const float*)d_in[0];
    const float* affine = (const float*)d_in[1];
    const int*   amask  = (const int*)  d_in[2];
    const float* w1     = (const float*)d_in[3];
    const float* b1     = (const float*)d_in[4];
    const float* ln_g   = (const float*)d_in[5];
    const float* ln_b   = (const float*)d_in[6];
    const float* w2     = (const float*)d_in[7];
    const float* b2     = (const float*)d_in[8];
    float* out = (float*)d_out;

    const size_t HB_ELEMS  = (size_t)MROWS * DK;     // 6.29 M
    const size_t W1_ELEMS  = (size_t)DK * DK;        // 2.36 M
    const size_t W2_ELEMS  = (size_t)OUTC * DK;      // 35 K
    const size_t FAST_BYTES = (2 * HB_ELEMS + W1_ELEMS + W2_ELEMS) * sizeof(unsigned short);

    unsigned short* Hb = (unsigned short*)d_ws;

    if (ws_size >= FAST_BYTES) {
        // workspace layout (bf16): Hb | xb | w1b | w2b  (~30 MB)
        unsigned short* xb  = Hb  + HB_ELEMS;
        unsigned short* w1b = xb  + HB_ELEMS;
        unsigned short* w2b = w1b + W1_ELEMS;

        convert_kernel<<<2048, 256, 0, stream>>>(x, w1, w2, xb, w1b, w2b);
        dim3 g1f(MROWS / 64, NOUT / 96);    // 64 x 16 = 1024 blocks = 4/CU
        gemm1_fast<<<g1f, 256, 0, stream>>>(xb, w1b, b1, Hb);
        head_fast<<<MROWS / 8, 256, 0, stream>>>(Hb, ln_g, ln_b, w2b, b2, affine, amask, out);
    } else {
        // known-good 149 µs path (workspace = Hb only, 12.6 MB)
        dim3 g1(MROWS / 128, NOUT / 128);   // 32 x 12 = 384 blocks
        gemm1_legacy<<<g1, 256, 0, stream>>>(x, w1, b1, Hb);
        head_legacy<<<MROWS / 8, 256, 0, stream>>>(Hb, ln_g, ln_b, w2, b2, affine, amask, out);
    }
}